// Round 9
// baseline (199.980 us; speedup 1.0000x reference)
//
#include <hip/hip_runtime.h>
#include <math.h>

// RelativeAttention on MI355X (gfx950). FP32 inputs/output; bf16 intermediates, fp32 accum.
// Round 9: occupancy attack. attn = split-K 8-wave blocks (32 waves/CU, halved serial chain,
// one LDS merge at end). GEMMs re-tiled 64x64 -> 1536/512 blocks (6/2 per CU vs 1.5/0.5).
// P stays register-resident (S^T = K*Q^T -> P already in 16x16x16 A-layout).
// B=8, C=256, H=W=32 (L=1024), nh=8, dk=dv=32, OUT_C=256.

typedef unsigned short u16;
typedef __bf16 bf16;
typedef bf16 bf16x8 __attribute__((ext_vector_type(8)));
typedef bf16 bf16x4 __attribute__((ext_vector_type(4)));
typedef short s16x4 __attribute__((ext_vector_type(4)));
typedef float f32x4 __attribute__((ext_vector_type(4)));
typedef float f32x4u __attribute__((ext_vector_type(4), aligned(4)));
typedef u16 u16x8 __attribute__((ext_vector_type(8)));
typedef u16 u16x4 __attribute__((ext_vector_type(4)));

#define DEVI __device__ __forceinline__

DEVI u16 bfbits(float f) { return __builtin_bit_cast(u16, (bf16)f); }

// 16x16x16 bf16 MFMA (K=16): A[m=lane&15][k=quad*4+j], B[k=quad*4+j][n=lane&15],
// C/D[row=quad*4+reg][col=lane&15]. (absmax-verified R7/R8.)
DEVI f32x4 pv_mfma(bf16x4 a, bf16x4 b, f32x4 c) {
#if __has_builtin(__builtin_amdgcn_mfma_f32_16x16x16bf16_1k)
    return __builtin_amdgcn_mfma_f32_16x16x16bf16_1k(
        __builtin_bit_cast(s16x4, a), __builtin_bit_cast(s16x4, b), c, 0, 0, 0);
#else
    asm("s_nop 1\n\tv_mfma_f32_16x16x16_bf16 %0, %1, %2, %0"
        : "+v"(c) : "v"(a), "v"(b));
    return c;
#endif
}

// ---------------- fused prep: transposes + bias prescale ----------------
__global__ __launch_bounds__(256) void prep(const float* __restrict__ X,
                                            const float* __restrict__ Qw, const float* __restrict__ Kw,
                                            const float* __restrict__ Vw, const float* __restrict__ Fw,
                                            const float* __restrict__ RB,
                                            u16* __restrict__ XF, u16* __restrict__ WT,
                                            float* __restrict__ RBs) {
    __shared__ u16 t[64 * 65];
    const int blk = blockIdx.x, tid = threadIdx.x;
    if (blk < 576) {
        const float* src;
        int cbase, rbase, rows_total;
        u16* dst;
        if (blk < 512) {
            const int b = blk >> 6;
            cbase = (blk & 3) * 64; rbase = ((blk >> 2) & 15) * 64;
            src = X + (size_t)b * 256 * 1024; dst = XF + (size_t)b * 1024 * 256;
            rows_total = 1024;
        } else {
            const int t2 = blk - 512, wsel = t2 >> 4;
            cbase = (t2 & 3) * 64; rbase = ((t2 >> 2) & 3) * 64;
            src = wsel == 0 ? Qw : wsel == 1 ? Kw : wsel == 2 ? Vw : Fw;
            dst = WT + (size_t)wsel * 256 * 256;
            rows_total = 256;
        }
        const int w = tid >> 6, r = tid & 63;
#pragma unroll
        for (int i = 0; i < 16; i++) {
            const int c = w * 16 + i;
            t[c * 65 + r] = bfbits(src[(size_t)(cbase + c) * rows_total + rbase + r]);
        }
        __syncthreads();
#pragma unroll
        for (int i = 0; i < 2; i++) {
            const int idx = i * 256 + tid;
            const int r2 = idx >> 3, cg = idx & 7;
            u16x8 v;
#pragma unroll
            for (int j = 0; j < 8; j++) v[j] = t[(cg * 8 + j) * 65 + r2];
            *(u16x8*)&dst[(size_t)(rbase + r2) * 256 + cbase + cg * 8] = v;
        }
    } else {
        const int n = 8 * 3969;
        for (int i = (blk - 576) * 256 + tid; i < n; i += 32 * 256)
            RBs[i] = RB[i] * 1.44269504f;
    }
}

// ---------------- unified GEMM: D[m][n] = sum_k A[m][k]*Bt[n][k], K=256, bf16 in ----------------
// 64x64 tile, BK=32, 4 waves each 32x32 (2x2 frags). One 16B staged load/thread/array/tile.
// pass 0 (grid 1536): blocks 0..1023 QK proj (q prescaled log2e, k) ; 1024..1535 V^T proj.
// pass 2 (grid 512): FF -> fp32 out (b,chan,l) + bias.
__global__ __launch_bounds__(256, 6) void gemm_fused(const u16* __restrict__ xf, const u16* __restrict__ wt,
                                                     u16* __restrict__ q, u16* __restrict__ kk,
                                                     u16* __restrict__ vt, const u16* __restrict__ ob,
                                                     float* __restrict__ outf, const float* __restrict__ ffb,
                                                     int base_mode) {
    __shared__ __align__(16) u16 lA[64 * 32];
    __shared__ __align__(16) u16 lB[64 * 32];
    const int tid = threadIdx.x;
    const int wave = tid >> 6, lane = tid & 63;
    const int quad = lane >> 4, l15 = lane & 15;

    int mode, mbase, nbase;
    const u16 *A, *Bt;
    if (base_mode == 2) {
        mode = 2; A = wt + 768 * 256; Bt = ob;               // M=256, N=8192
        mbase = (blockIdx.x & 3) * 64; nbase = (blockIdx.x >> 2) * 64;
    } else if (blockIdx.x < 1024) {
        mode = 0; A = xf; Bt = wt;                            // M=8192, N=512
        mbase = (blockIdx.x >> 3) * 64; nbase = (blockIdx.x & 7) * 64;
    } else {
        mode = 1; A = wt + 512 * 256; Bt = xf;                // M=256, N=8192
        const int t = blockIdx.x - 1024;
        mbase = (t & 3) * 64; nbase = (t >> 2) * 64;
    }

    const int m0 = (wave >> 1) * 32, n0 = (wave & 1) * 32;
    const int srow = tid >> 2;          // 0..63
    const int k8 = (tid & 3) * 8;       // k-offset within BK=32

    f32x4 acc[2][2];
#pragma unroll
    for (int i = 0; i < 2; i++)
#pragma unroll
        for (int j = 0; j < 2; j++) acc[i][j] = f32x4{0.f, 0.f, 0.f, 0.f};

    for (int kb = 0; kb < 256; kb += 32) {
        __syncthreads();
        *(u16x8*)&lA[srow * 32 + k8] = *(const u16x8*)&A[(size_t)(mbase + srow) * 256 + kb + k8];
        *(u16x8*)&lB[srow * 32 + k8] = *(const u16x8*)&Bt[(size_t)(nbase + srow) * 256 + kb + k8];
        __syncthreads();
        bf16x8 af[2], bfr[2];
#pragma unroll
        for (int i = 0; i < 2; i++) af[i] = *(const bf16x8*)&lA[(m0 + i * 16 + l15) * 32 + quad * 8];
#pragma unroll
        for (int j = 0; j < 2; j++) bfr[j] = *(const bf16x8*)&lB[(n0 + j * 16 + l15) * 32 + quad * 8];
#pragma unroll
        for (int i = 0; i < 2; i++)
#pragma unroll
            for (int j = 0; j < 2; j++)
                acc[i][j] = __builtin_amdgcn_mfma_f32_16x16x32_bf16(af[i], bfr[j], acc[i][j], 0, 0, 0);
    }

    // epilogue: C-layout col = lane&15, row = quad*4 + reg
#pragma unroll
    for (int i = 0; i < 2; i++) {
#pragma unroll
        for (int j = 0; j < 2; j++) {
#pragma unroll
            for (int r = 0; r < 4; r++) {
                const int gm = mbase + m0 + i * 16 + quad * 4 + r;
                const int gn = nbase + n0 + j * 16 + l15;
                float v = acc[i][j][r];
                if (mode == 0) {           // gm = (b,l), gn = qkv column
                    const int b = gm >> 10, l = gm & 1023;
                    int n = gn;
                    u16* dst = q;
                    if (n >= 256) { n -= 256; dst = kk; }
                    else v *= 1.44269504f;                 // fold log2e into q
                    const int h = n >> 5, d = n & 31;
                    dst[(((size_t)(b * 8 + h) * 1024 + l) << 5) + d] = bfbits(v);
                } else if (mode == 1) {    // gm = v column, gn = (b,l) -> v^T
                    const int h = gm >> 5, d = gm & 31;
                    const int b = gn >> 10, l = gn & 1023;
                    vt[(((size_t)(b * 8 + h) * 32 + d) << 10) + l] = bfbits(v);
                } else {                   // gm = out chan, gn = (b,l) -> fp32 out
                    const int b = gn >> 10, l = gn & 1023;
                    outf[(((size_t)(b * 256 + gm)) << 10) + l] = v + ffb[gm];
                }
            }
        }
    }
}

// ---------------- flash attention: split-K, register-resident P ----------------
// 1024 blocks x 512 threads (8 waves). XCD swizzle: 16 q-tiles of one (b,h) share blk&7.
// Wave w: qsub = w&3 (16 Q rows), half = w>>2 -> chunks [half*16, half*16+16).
// Per chunk: S^T = K*Q^T (swapped operands) -> bias+exp2 -> P already in 16x16x16 A-layout
// -> 4x PV MFMA. Max-free softmax => halves merge by simple addition (LDS, one barrier).
__global__ __launch_bounds__(512, 8) void attn(const u16* __restrict__ Q, const u16* __restrict__ Kb,
                                               const u16* __restrict__ Vt, const float* __restrict__ RBs,
                                               u16* __restrict__ O) {
    __shared__ float merge[4 * 64 * 9];   // [qsub][lane][o_lo(4) o_hi(4) lsum] = 9 KB
    const int tid = threadIdx.x;
    const int wave = tid >> 6, lane = tid & 63;
    const int quad = lane >> 4, l15 = lane & 15;
    const int qsub = wave & 3, half = wave >> 2;
    const int blk = blockIdx.x;
    const int bh = ((blk >> 7) << 3) + (blk & 7);
    const int qt = (blk >> 3) & 15;
    const int b = bh >> 3, h = bh & 7;
    const int qbase = qt * 64 + qsub * 16;
    const size_t bhL = (size_t)bh * 1024;

    const bf16x8 qf = *(const bf16x8*)&Q[(bhL + qbase + l15) * 32 + quad * 8];   // Q[query=l15][d]
    const float* brow0 = RBs + (size_t)h * 3969
                         + (32 - (qbase >> 5)) * 32 + 32 - (qbase & 31) - l15 + quad * 4;
    const u16* vrow_lo = &Vt[(((size_t)bh * 32) + l15) << 10];        // V^T row d=l15
    const u16* vrow_hi = &Vt[(((size_t)bh * 32) + 16 + l15) << 10];   // V^T row d=16+l15

    float lsum = 0.f;
    f32x4 o_lo{0.f, 0.f, 0.f, 0.f}, o_hi{0.f, 0.f, 0.f, 0.f};

    const int c0 = half * 16;
#pragma unroll 4
    for (int c = c0; c < c0 + 16; c++) {             // key chunk = one image row (yj == c)
        const int kb = c * 32;
        const bf16x8 kf0 = *(const bf16x8*)&Kb[(bhL + kb + l15) * 32 + quad * 8];
        const bf16x8 kf1 = *(const bf16x8*)&Kb[(bhL + kb + 16 + l15) * 32 + quad * 8];
        const bf16x4 v00 = __builtin_bit_cast(bf16x4, *(const u16x4*)&vrow_lo[kb + quad * 4]);
        const bf16x4 v10 = __builtin_bit_cast(bf16x4, *(const u16x4*)&vrow_lo[kb + 16 + quad * 4]);
        const bf16x4 v01 = __builtin_bit_cast(bf16x4, *(const u16x4*)&vrow_hi[kb + quad * 4]);
        const bf16x4 v11 = __builtin_bit_cast(bf16x4, *(const u16x4*)&vrow_hi[kb + 16 + quad * 4]);
        const f32x4u b0 = *(const f32x4u*)(brow0 + c * 32);
        const f32x4u b1 = *(const f32x4u*)(brow0 + c * 32 + 16);
        const f32x4 z{0.f, 0.f, 0.f, 0.f};
        // swapped operands: S^T = K * Q^T -> lane holds S[query=l15][key=quad*4+r]
        f32x4 s0 = __builtin_amdgcn_mfma_f32_16x16x32_bf16(kf0, qf, z, 0, 0, 0);
        f32x4 s1 = __builtin_amdgcn_mfma_f32_16x16x32_bf16(kf1, qf, z, 0, 0, 0);
        bf16x4 p0, p1;
#pragma unroll
        for (int r = 0; r < 4; r++) {
            const float e0 = exp2f(s0[r] + b0[r]);
            const float e1 = exp2f(s1[r] + b1[r]);
            lsum += e0 + e1;
            p0[r] = (bf16)e0;
            p1[r] = (bf16)e1;
        }
        o_lo = pv_mfma(p0, v00, o_lo);
        o_hi = pv_mfma(p0, v01, o_hi);
        o_lo = pv_mfma(p1, v10, o_lo);
        o_hi = pv_mfma(p1, v11, o_hi);
    }
    // reduce half-range lsum across quads: per-lane value = half-sum for query l15
    lsum += __shfl_xor(lsum, 16);
    lsum += __shfl_xor(lsum, 32);

    float* m = &merge[(qsub * 64 + lane) * 9];
    if (half == 1) {
#pragma unroll
        for (int r = 0; r < 4; r++) { m[r] = o_lo[r]; m[4 + r] = o_hi[r]; }
        m[8] = lsum;
    }
    __syncthreads();
    if (half == 0) {
#pragma unroll
        for (int r = 0; r < 4; r++) { o_lo[r] += m[r]; o_hi[r] += m[4 + r]; }
        lsum += m[8];
#pragma unroll
        for (int r = 0; r < 4; r++) {
            const float inv = 1.f / __shfl(lsum, quad * 4 + r);
            const int i = qbase + quad * 4 + r;
            O[((size_t)(b * 1024 + i) * 256) + h * 32 + l15] = bfbits(o_lo[r] * inv);
            O[((size_t)(b * 1024 + i) * 256) + h * 32 + 16 + l15] = bfbits(o_hi[r] * inv);
        }
    }
}

extern "C" void kernel_launch(void* const* d_in, const int* in_sizes, int n_in,
                              void* d_out, int out_size, void* d_ws, size_t ws_size,
                              hipStream_t stream) {
    const float* x   = (const float*)d_in[0];
    const float* Qw  = (const float*)d_in[1];
    const float* Kw  = (const float*)d_in[2];
    const float* Vw  = (const float*)d_in[3];
    const float* Fw  = (const float*)d_in[4];
    const float* ffb = (const float*)d_in[5];
    const float* RB  = (const float*)d_in[6];
    // d_in[7] = rel_idx (int32): deterministic, computed analytically in-kernel.

    u16* ws = (u16*)d_ws;
    u16* xf = ws;                   // 8192 x 256 bf16 (4 MB)   ... later reused as ob
    u16* wt = xf + 2097152;         // 1024 x 256 bf16 (0.5 MB) [Qw^T|Kw^T|Vw^T|ffw^T]
    u16* q  = wt + 262144;          // (b,h,l,d)  bf16 (4 MB), pre-scaled by log2e
    u16* kk = q  + 2097152;         // (b,h,l,d)  bf16 (4 MB)
    u16* vt = kk + 2097152;         // (b,h,d,l)  bf16 (4 MB)
    float* RBs = (float*)(vt + 2097152);   // 8 x 3969 fp32 (127 KB), bias * log2e
    u16* ob = xf;                   // (b,l,h*32+d) bf16 — aliases xf (dead after V proj)

    prep<<<dim3(608), 256, 0, stream>>>(x, Qw, Kw, Vw, Fw, RB, xf, wt, RBs);
    gemm_fused<<<dim3(1536), 256, 0, stream>>>(xf, wt, q, kk, vt, nullptr, nullptr, nullptr, 0); // QK + V^T
    attn<<<dim3(1024), 512, 0, stream>>>(q, kk, vt, RBs, ob);
    gemm_fused<<<dim3(512), 256, 0, stream>>>(xf, wt, q, kk, vt, ob, (float*)d_out, ffb, 2);     // FF
}

// Round 10
// 137.084 us; speedup vs baseline: 1.4588x; 1.4588x over previous
//
#include <hip/hip_runtime.h>
#include <math.h>

// RelativeAttention on MI355X (gfx950). FP32 inputs/output; bf16 intermediates, fp32 accum.
// Round 10: attn = async global_load_lds double-buffered K/V tiles SHARED by all 4 waves
// (kills 4x redundant loads + compiler load-sinking; explicit pipeline the compiler can't
// defeat). 256 thr, no split-K, no spill. P register-resident (S^T = K*Q^T trick).
// B=8, C=256, H=W=32 (L=1024), nh=8, dk=dv=32, OUT_C=256.

typedef unsigned short u16;
typedef __bf16 bf16;
typedef bf16 bf16x8 __attribute__((ext_vector_type(8)));
typedef bf16 bf16x4 __attribute__((ext_vector_type(4)));
typedef short s16x4 __attribute__((ext_vector_type(4)));
typedef float f32x4 __attribute__((ext_vector_type(4)));
typedef float f32x4u __attribute__((ext_vector_type(4), aligned(4)));
typedef u16 u16x8 __attribute__((ext_vector_type(8)));
typedef u16 u16x4 __attribute__((ext_vector_type(4)));

#define DEVI __device__ __forceinline__

DEVI u16 bfbits(float f) { return __builtin_bit_cast(u16, (bf16)f); }

DEVI void async_cp16(const u16* g, u16* l) {
    __builtin_amdgcn_global_load_lds((const __attribute__((address_space(1))) void*)g,
                                     (__attribute__((address_space(3))) void*)l, 16, 0, 0);
}

// 16x16x16 bf16 MFMA (K=16): A[m=lane&15][k=quad*4+j], B[k=quad*4+j][n=lane&15],
// C/D[row=quad*4+reg][col=lane&15]. (absmax-verified R7/R8/R9.)
DEVI f32x4 pv_mfma(bf16x4 a, bf16x4 b, f32x4 c) {
#if __has_builtin(__builtin_amdgcn_mfma_f32_16x16x16bf16_1k)
    return __builtin_amdgcn_mfma_f32_16x16x16bf16_1k(
        __builtin_bit_cast(s16x4, a), __builtin_bit_cast(s16x4, b), c, 0, 0, 0);
#else
    asm("s_nop 1\n\tv_mfma_f32_16x16x16_bf16 %0, %1, %2, %0"
        : "+v"(c) : "v"(a), "v"(b));
    return c;
#endif
}

// ---------------- fused prep: transposes + bias prescale ----------------
__global__ __launch_bounds__(256) void prep(const float* __restrict__ X,
                                            const float* __restrict__ Qw, const float* __restrict__ Kw,
                                            const float* __restrict__ Vw, const float* __restrict__ Fw,
                                            const float* __restrict__ RB,
                                            u16* __restrict__ XF, u16* __restrict__ WT,
                                            float* __restrict__ RBs) {
    __shared__ u16 t[64 * 65];
    const int blk = blockIdx.x, tid = threadIdx.x;
    if (blk < 576) {
        const float* src;
        int cbase, rbase, rows_total;
        u16* dst;
        if (blk < 512) {
            const int b = blk >> 6;
            cbase = (blk & 3) * 64; rbase = ((blk >> 2) & 15) * 64;
            src = X + (size_t)b * 256 * 1024; dst = XF + (size_t)b * 1024 * 256;
            rows_total = 1024;
        } else {
            const int t2 = blk - 512, wsel = t2 >> 4;
            cbase = (t2 & 3) * 64; rbase = ((t2 >> 2) & 3) * 64;
            src = wsel == 0 ? Qw : wsel == 1 ? Kw : wsel == 2 ? Vw : Fw;
            dst = WT + (size_t)wsel * 256 * 256;
            rows_total = 256;
        }
        const int w = tid >> 6, r = tid & 63;
#pragma unroll
        for (int i = 0; i < 16; i++) {
            const int c = w * 16 + i;
            t[c * 65 + r] = bfbits(src[(size_t)(cbase + c) * rows_total + rbase + r]);
        }
        __syncthreads();
#pragma unroll
        for (int i = 0; i < 2; i++) {
            const int idx = i * 256 + tid;
            const int r2 = idx >> 3, cg = idx & 7;
            u16x8 v;
#pragma unroll
            for (int j = 0; j < 8; j++) v[j] = t[(cg * 8 + j) * 65 + r2];
            *(u16x8*)&dst[(size_t)(rbase + r2) * 256 + cbase + cg * 8] = v;
        }
    } else {
        const int n = 8 * 3969;
        for (int i = (blk - 576) * 256 + tid; i < n; i += 32 * 256)
            RBs[i] = RB[i] * 1.44269504f;
    }
}

// ---------------- unified GEMM: D[m][n] = sum_k A[m][k]*Bt[n][k], K=256, bf16 in ----------------
// 64x64 tile, BK=32, 4 waves each 32x32 (2x2 frags).
__global__ __launch_bounds__(256, 6) void gemm_fused(const u16* __restrict__ xf, const u16* __restrict__ wt,
                                                     u16* __restrict__ q, u16* __restrict__ kk,
                                                     u16* __restrict__ vt, const u16* __restrict__ ob,
                                                     float* __restrict__ outf, const float* __restrict__ ffb,
                                                     int base_mode) {
    __shared__ __align__(16) u16 lA[64 * 32];
    __shared__ __align__(16) u16 lB[64 * 32];
    const int tid = threadIdx.x;
    const int wave = tid >> 6, lane = tid & 63;
    const int quad = lane >> 4, l15 = lane & 15;

    int mode, mbase, nbase;
    const u16 *A, *Bt;
    if (base_mode == 2) {
        mode = 2; A = wt + 768 * 256; Bt = ob;               // M=256, N=8192
        mbase = (blockIdx.x & 3) * 64; nbase = (blockIdx.x >> 2) * 64;
    } else if (blockIdx.x < 1024) {
        mode = 0; A = xf; Bt = wt;                            // M=8192, N=512
        mbase = (blockIdx.x >> 3) * 64; nbase = (blockIdx.x & 7) * 64;
    } else {
        mode = 1; A = wt + 512 * 256; Bt = xf;                // M=256, N=8192
        const int t = blockIdx.x - 1024;
        mbase = (t & 3) * 64; nbase = (t >> 2) * 64;
    }

    const int m0 = (wave >> 1) * 32, n0 = (wave & 1) * 32;
    const int srow = tid >> 2;
    const int k8 = (tid & 3) * 8;

    f32x4 acc[2][2];
#pragma unroll
    for (int i = 0; i < 2; i++)
#pragma unroll
        for (int j = 0; j < 2; j++) acc[i][j] = f32x4{0.f, 0.f, 0.f, 0.f};

    for (int kb = 0; kb < 256; kb += 32) {
        __syncthreads();
        *(u16x8*)&lA[srow * 32 + k8] = *(const u16x8*)&A[(size_t)(mbase + srow) * 256 + kb + k8];
        *(u16x8*)&lB[srow * 32 + k8] = *(const u16x8*)&Bt[(size_t)(nbase + srow) * 256 + kb + k8];
        __syncthreads();
        bf16x8 af[2], bfr[2];
#pragma unroll
        for (int i = 0; i < 2; i++) af[i] = *(const bf16x8*)&lA[(m0 + i * 16 + l15) * 32 + quad * 8];
#pragma unroll
        for (int j = 0; j < 2; j++) bfr[j] = *(const bf16x8*)&lB[(n0 + j * 16 + l15) * 32 + quad * 8];
#pragma unroll
        for (int i = 0; i < 2; i++)
#pragma unroll
            for (int j = 0; j < 2; j++)
                acc[i][j] = __builtin_amdgcn_mfma_f32_16x16x32_bf16(af[i], bfr[j], acc[i][j], 0, 0, 0);
    }

    // epilogue: C-layout col = lane&15, row = quad*4 + reg
#pragma unroll
    for (int i = 0; i < 2; i++) {
#pragma unroll
        for (int j = 0; j < 2; j++) {
#pragma unroll
            for (int r = 0; r < 4; r++) {
                const int gm = mbase + m0 + i * 16 + quad * 4 + r;
                const int gn = nbase + n0 + j * 16 + l15;
                float v = acc[i][j][r];
                if (mode == 0) {
                    const int b = gm >> 10, l = gm & 1023;
                    int n = gn;
                    u16* dst = q;
                    if (n >= 256) { n -= 256; dst = kk; }
                    else v *= 1.44269504f;                 // fold log2e into q
                    const int h = n >> 5, d = n & 31;
                    dst[(((size_t)(b * 8 + h) * 1024 + l) << 5) + d] = bfbits(v);
                } else if (mode == 1) {
                    const int h = gm >> 5, d = gm & 31;
                    const int b = gn >> 10, l = gn & 1023;
                    vt[(((size_t)(b * 8 + h) * 32 + d) << 10) + l] = bfbits(v);
                } else {
                    const int b = gn >> 10, l = gn & 1023;
                    outf[(((size_t)(b * 256 + gm)) << 10) + l] = v + ffb[gm];
                }
            }
        }
    }
}

// ---------------- flash attention: async-LDS double-buffered K/V, register-resident P ----------
// 1024 blocks x 4 waves (one q-subtile each). XCD swizzle: 16 q-tiles of one (b,h) share blk&7.
// Wave 0 async-stages chunk c+1's K tile (32 keys x 32 d, 2 KB) + V tile (32 d x 32 keys, 2 KB)
// into LDS buf[nxt] while ALL waves compute chunk c from buf[cur]; one barrier per chunk
// (wave 0's vmcnt drains before s_barrier -> data visible; prefetch latency hidden by compute).
// Per chunk: S^T = K*Q^T (swapped operands) -> bias+exp2 -> P already in 16x16x16 A-layout
// -> 4x PV MFMA. Max-free softmax; normalize at end.
__global__ __launch_bounds__(256, 4) void attn(const u16* __restrict__ Q, const u16* __restrict__ Kb,
                                               const u16* __restrict__ Vt, const float* __restrict__ RBs,
                                               u16* __restrict__ O) {
    __shared__ __align__(16) u16 kbuf[2][32 * 32];   // [key][d]
    __shared__ __align__(16) u16 vbuf[2][32 * 32];   // [d][key]
    const int tid = threadIdx.x;
    const int wave = tid >> 6, lane = tid & 63;
    const int quad = lane >> 4, l15 = lane & 15;
    const int blk = blockIdx.x;
    const int bh = ((blk >> 7) << 3) + (blk & 7);
    const int qt = (blk >> 3) & 15;
    const int b = bh >> 3, h = bh & 7;
    const int qbase = qt * 64 + wave * 16;
    const size_t bhL = (size_t)bh * 1024;

    const bf16x8 qf = *(const bf16x8*)&Q[(bhL + qbase + l15) * 32 + quad * 8];   // Q[query=l15][d]
    const float* brow0 = RBs + (size_t)h * 3969
                         + (32 - (qbase >> 5)) * 32 + 32 - (qbase & 31) - l15 + quad * 4;
    // staging source addresses (wave 0 only uses these)
    const u16* ksrc0 = &Kb[bhL * 32];                            // + kb*32 per chunk, contiguous 2KB
    const u16* vsrc_lo = &Vt[(((size_t)bh * 32) + (lane >> 2)) << 10];        // rows 0..15 by lane/4
    const u16* vsrc_hi = &Vt[(((size_t)bh * 32) + 16 + (lane >> 2)) << 10];   // rows 16..31
    const int vcol = (lane & 3) * 8;                             // 16B column slice within row

    float lsum = 0.f;
    f32x4 o_lo{0.f, 0.f, 0.f, 0.f}, o_hi{0.f, 0.f, 0.f, 0.f};

#define STAGE(buf, c) do {                                                   \
        const int kb_ = (c) * 32;                                            \
        async_cp16(ksrc0 + kb_ * 32 + lane * 8, &kbuf[buf][0]);              \
        async_cp16(ksrc0 + kb_ * 32 + 512 + lane * 8, &kbuf[buf][512]);      \
        async_cp16(vsrc_lo + kb_ + vcol, &vbuf[buf][0]);                     \
        async_cp16(vsrc_hi + kb_ + vcol, &vbuf[buf][512]);                   \
    } while (0)

    if (wave == 0) STAGE(0, 0);
    __syncthreads();

    for (int c = 0; c < 32; c++) {                   // key chunk = one image row (yj == c)
        const int cur = c & 1;
        if (wave == 0 && c < 31) STAGE(cur ^ 1, c + 1);   // prefetch next while computing
        const bf16x8 kf0 = *(const bf16x8*)&kbuf[cur][l15 * 32 + quad * 8];
        const bf16x8 kf1 = *(const bf16x8*)&kbuf[cur][(16 + l15) * 32 + quad * 8];
        const bf16x4 v00 = __builtin_bit_cast(bf16x4, *(const u16x4*)&vbuf[cur][l15 * 32 + quad * 4]);
        const bf16x4 v10 = __builtin_bit_cast(bf16x4, *(const u16x4*)&vbuf[cur][l15 * 32 + 16 + quad * 4]);
        const bf16x4 v01 = __builtin_bit_cast(bf16x4, *(const u16x4*)&vbuf[cur][(16 + l15) * 32 + quad * 4]);
        const bf16x4 v11 = __builtin_bit_cast(bf16x4, *(const u16x4*)&vbuf[cur][(16 + l15) * 32 + 16 + quad * 4]);
        const f32x4u b0 = *(const f32x4u*)(brow0 + c * 32);
        const f32x4u b1 = *(const f32x4u*)(brow0 + c * 32 + 16);
        const f32x4 z{0.f, 0.f, 0.f, 0.f};
        // swapped operands: S^T = K * Q^T -> lane holds S[query=l15][key=quad*4+r]
        f32x4 s0 = __builtin_amdgcn_mfma_f32_16x16x32_bf16(kf0, qf, z, 0, 0, 0);
        f32x4 s1 = __builtin_amdgcn_mfma_f32_16x16x32_bf16(kf1, qf, z, 0, 0, 0);
        bf16x4 p0, p1;
#pragma unroll
        for (int r = 0; r < 4; r++) {
            const float e0 = exp2f(s0[r] + b0[r]);
            const float e1 = exp2f(s1[r] + b1[r]);
            lsum += e0 + e1;
            p0[r] = (bf16)e0;
            p1[r] = (bf16)e1;
        }
        o_lo = pv_mfma(p0, v00, o_lo);
        o_hi = pv_mfma(p0, v01, o_hi);
        o_lo = pv_mfma(p1, v10, o_lo);
        o_hi = pv_mfma(p1, v11, o_hi);
        __syncthreads();   // stage(nxt) drained (wave0) + all waves done reading cur
    }
#undef STAGE
    // lsum on lane = partial row-sum for query l15; finish across quads
    lsum += __shfl_xor(lsum, 16);
    lsum += __shfl_xor(lsum, 32);
#pragma unroll
    for (int r = 0; r < 4; r++) {
        const float inv = 1.f / __shfl(lsum, quad * 4 + r);
        const int i = qbase + quad * 4 + r;
        O[((size_t)(b * 1024 + i) * 256) + h * 32 + l15] = bfbits(o_lo[r] * inv);
        O[((size_t)(b * 1024 + i) * 256) + h * 32 + 16 + l15] = bfbits(o_hi[r] * inv);
    }
}

extern "C" void kernel_launch(void* const* d_in, const int* in_sizes, int n_in,
                              void* d_out, int out_size, void* d_ws, size_t ws_size,
                              hipStream_t stream) {
    const float* x   = (const float*)d_in[0];
    const float* Qw  = (const float*)d_in[1];
    const float* Kw  = (const float*)d_in[2];
    const float* Vw  = (const float*)d_in[3];
    const float* Fw  = (const float*)d_in[4];
    const float* ffb = (const float*)d_in[5];
    const float* RB  = (const float*)d_in[6];
    // d_in[7] = rel_idx (int32): deterministic, computed analytically in-kernel.

    u16* ws = (u16*)d_ws;
    u16* xf = ws;                   // 8192 x 256 bf16 (4 MB)   ... later reused as ob
    u16* wt = xf + 2097152;         // 1024 x 256 bf16 (0.5 MB) [Qw^T|Kw^T|Vw^T|ffw^T]
    u16* q  = wt + 262144;          // (b,h,l,d)  bf16 (4 MB), pre-scaled by log2e
    u16* kk = q  + 2097152;         // (b,h,l,d)  bf16 (4 MB)
    u16* vt = kk + 2097152;         // (b,h,d,l)  bf16 (4 MB)
    float* RBs = (float*)(vt + 2097152);   // 8 x 3969 fp32 (127 KB), bias * log2e
    u16* ob = xf;                   // (b,l,h*32+d) bf16 — aliases xf (dead after V proj)

    prep<<<dim3(608), 256, 0, stream>>>(x, Qw, Kw, Vw, Fw, RB, xf, wt, RBs);
    gemm_fused<<<dim3(1536), 256, 0, stream>>>(xf, wt, q, kk, vt, nullptr, nullptr, nullptr, 0); // QK + V^T
    attn<<<dim3(1024), 256, 0, stream>>>(q, kk, vt, RBs, ob);
    gemm_fused<<<dim3(512), 256, 0, stream>>>(xf, wt, q, kk, vt, ob, (float*)d_out, ffb, 2);     // FF
}

// Round 11
// 130.007 us; speedup vs baseline: 1.5382x; 1.0544x over previous
//
#include <hip/hip_runtime.h>
#include <math.h>

// RelativeAttention on MI355X (gfx950). FP32 inputs/output; bf16 intermediates, fp32 accum.
// Round 11: XOR-swizzled async-LDS staging in attn. global_load_lds forbids padding (lane x 16B
// contiguous scatter, m104), so conflicts are killed by permuting WHICH global chunk each lane
// stages: LDS chunk [row][c] holds global [row][c ^ ((row>>1)&3)]. K b128 reads become
// conflict-free (chunk mod 8 spans all 8 groups per 8-lane phase); V b64 reads drop to 2-way
// (free, m136). Readers XOR the same term. Everything else unchanged from R10.
// B=8, C=256, H=W=32 (L=1024), nh=8, dk=dv=32, OUT_C=256.

typedef unsigned short u16;
typedef __bf16 bf16;
typedef bf16 bf16x8 __attribute__((ext_vector_type(8)));
typedef bf16 bf16x4 __attribute__((ext_vector_type(4)));
typedef short s16x4 __attribute__((ext_vector_type(4)));
typedef float f32x4 __attribute__((ext_vector_type(4)));
typedef float f32x4u __attribute__((ext_vector_type(4), aligned(4)));
typedef u16 u16x8 __attribute__((ext_vector_type(8)));
typedef u16 u16x4 __attribute__((ext_vector_type(4)));

#define DEVI __device__ __forceinline__

DEVI u16 bfbits(float f) { return __builtin_bit_cast(u16, (bf16)f); }

DEVI void async_cp16(const u16* g, u16* l) {
    __builtin_amdgcn_global_load_lds((const __attribute__((address_space(1))) void*)g,
                                     (__attribute__((address_space(3))) void*)l, 16, 0, 0);
}

// 16x16x16 bf16 MFMA (K=16): A[m=lane&15][k=quad*4+j], B[k=quad*4+j][n=lane&15],
// C/D[row=quad*4+reg][col=lane&15]. (absmax-verified R7-R10.)
DEVI f32x4 pv_mfma(bf16x4 a, bf16x4 b, f32x4 c) {
#if __has_builtin(__builtin_amdgcn_mfma_f32_16x16x16bf16_1k)
    return __builtin_amdgcn_mfma_f32_16x16x16bf16_1k(
        __builtin_bit_cast(s16x4, a), __builtin_bit_cast(s16x4, b), c, 0, 0, 0);
#else
    asm("s_nop 1\n\tv_mfma_f32_16x16x16_bf16 %0, %1, %2, %0"
        : "+v"(c) : "v"(a), "v"(b));
    return c;
#endif
}

// ---------------- fused prep: transposes + bias prescale ----------------
__global__ __launch_bounds__(256) void prep(const float* __restrict__ X,
                                            const float* __restrict__ Qw, const float* __restrict__ Kw,
                                            const float* __restrict__ Vw, const float* __restrict__ Fw,
                                            const float* __restrict__ RB,
                                            u16* __restrict__ XF, u16* __restrict__ WT,
                                            float* __restrict__ RBs) {
    __shared__ u16 t[64 * 65];
    const int blk = blockIdx.x, tid = threadIdx.x;
    if (blk < 576) {
        const float* src;
        int cbase, rbase, rows_total;
        u16* dst;
        if (blk < 512) {
            const int b = blk >> 6;
            cbase = (blk & 3) * 64; rbase = ((blk >> 2) & 15) * 64;
            src = X + (size_t)b * 256 * 1024; dst = XF + (size_t)b * 1024 * 256;
            rows_total = 1024;
        } else {
            const int t2 = blk - 512, wsel = t2 >> 4;
            cbase = (t2 & 3) * 64; rbase = ((t2 >> 2) & 3) * 64;
            src = wsel == 0 ? Qw : wsel == 1 ? Kw : wsel == 2 ? Vw : Fw;
            dst = WT + (size_t)wsel * 256 * 256;
            rows_total = 256;
        }
        const int w = tid >> 6, r = tid & 63;
#pragma unroll
        for (int i = 0; i < 16; i++) {
            const int c = w * 16 + i;
            t[c * 65 + r] = bfbits(src[(size_t)(cbase + c) * rows_total + rbase + r]);
        }
        __syncthreads();
#pragma unroll
        for (int i = 0; i < 2; i++) {
            const int idx = i * 256 + tid;
            const int r2 = idx >> 3, cg = idx & 7;
            u16x8 v;
#pragma unroll
            for (int j = 0; j < 8; j++) v[j] = t[(cg * 8 + j) * 65 + r2];
            *(u16x8*)&dst[(size_t)(rbase + r2) * 256 + cbase + cg * 8] = v;
        }
    } else {
        const int n = 8 * 3969;
        for (int i = (blk - 576) * 256 + tid; i < n; i += 32 * 256)
            RBs[i] = RB[i] * 1.44269504f;
    }
}

// ---------------- unified GEMM: D[m][n] = sum_k A[m][k]*Bt[n][k], K=256, bf16 in ----------------
// 64x64 tile, BK=32, 4 waves each 32x32 (2x2 frags).
__global__ __launch_bounds__(256, 6) void gemm_fused(const u16* __restrict__ xf, const u16* __restrict__ wt,
                                                     u16* __restrict__ q, u16* __restrict__ kk,
                                                     u16* __restrict__ vt, const u16* __restrict__ ob,
                                                     float* __restrict__ outf, const float* __restrict__ ffb,
                                                     int base_mode) {
    __shared__ __align__(16) u16 lA[64 * 32];
    __shared__ __align__(16) u16 lB[64 * 32];
    const int tid = threadIdx.x;
    const int wave = tid >> 6, lane = tid & 63;
    const int quad = lane >> 4, l15 = lane & 15;

    int mode, mbase, nbase;
    const u16 *A, *Bt;
    if (base_mode == 2) {
        mode = 2; A = wt + 768 * 256; Bt = ob;               // M=256, N=8192
        mbase = (blockIdx.x & 3) * 64; nbase = (blockIdx.x >> 2) * 64;
    } else if (blockIdx.x < 1024) {
        mode = 0; A = xf; Bt = wt;                            // M=8192, N=512
        mbase = (blockIdx.x >> 3) * 64; nbase = (blockIdx.x & 7) * 64;
    } else {
        mode = 1; A = wt + 512 * 256; Bt = xf;                // M=256, N=8192
        const int t = blockIdx.x - 1024;
        mbase = (t & 3) * 64; nbase = (t >> 2) * 64;
    }

    const int m0 = (wave >> 1) * 32, n0 = (wave & 1) * 32;
    const int srow = tid >> 2;
    const int k8 = (tid & 3) * 8;

    f32x4 acc[2][2];
#pragma unroll
    for (int i = 0; i < 2; i++)
#pragma unroll
        for (int j = 0; j < 2; j++) acc[i][j] = f32x4{0.f, 0.f, 0.f, 0.f};

    for (int kb = 0; kb < 256; kb += 32) {
        __syncthreads();
        *(u16x8*)&lA[srow * 32 + k8] = *(const u16x8*)&A[(size_t)(mbase + srow) * 256 + kb + k8];
        *(u16x8*)&lB[srow * 32 + k8] = *(const u16x8*)&Bt[(size_t)(nbase + srow) * 256 + kb + k8];
        __syncthreads();
        bf16x8 af[2], bfr[2];
#pragma unroll
        for (int i = 0; i < 2; i++) af[i] = *(const bf16x8*)&lA[(m0 + i * 16 + l15) * 32 + quad * 8];
#pragma unroll
        for (int j = 0; j < 2; j++) bfr[j] = *(const bf16x8*)&lB[(n0 + j * 16 + l15) * 32 + quad * 8];
#pragma unroll
        for (int i = 0; i < 2; i++)
#pragma unroll
            for (int j = 0; j < 2; j++)
                acc[i][j] = __builtin_amdgcn_mfma_f32_16x16x32_bf16(af[i], bfr[j], acc[i][j], 0, 0, 0);
    }

    // epilogue: C-layout col = lane&15, row = quad*4 + reg
#pragma unroll
    for (int i = 0; i < 2; i++) {
#pragma unroll
        for (int j = 0; j < 2; j++) {
#pragma unroll
            for (int r = 0; r < 4; r++) {
                const int gm = mbase + m0 + i * 16 + quad * 4 + r;
                const int gn = nbase + n0 + j * 16 + l15;
                float v = acc[i][j][r];
                if (mode == 0) {
                    const int b = gm >> 10, l = gm & 1023;
                    int n = gn;
                    u16* dst = q;
                    if (n >= 256) { n -= 256; dst = kk; }
                    else v *= 1.44269504f;                 // fold log2e into q
                    const int h = n >> 5, d = n & 31;
                    dst[(((size_t)(b * 8 + h) * 1024 + l) << 5) + d] = bfbits(v);
                } else if (mode == 1) {
                    const int h = gm >> 5, d = gm & 31;
                    const int b = gn >> 10, l = gn & 1023;
                    vt[(((size_t)(b * 8 + h) * 32 + d) << 10) + l] = bfbits(v);
                } else {
                    const int b = gn >> 10, l = gn & 1023;
                    outf[(((size_t)(b * 256 + gm)) << 10) + l] = v + ffb[gm];
                }
            }
        }
    }
}

// ---------------- flash attention: swizzled async-LDS double-buffered K/V ----------------
// 1024 blocks x 4 waves. XCD swizzle on blockIdx. Wave 0 async-stages chunk c+1's K tile
// (32 keys x 32 d) + V tile (32 d x 32 keys) with XOR-swizzled chunk columns; all waves
// compute chunk c; one barrier per chunk. S^T = K*Q^T -> bias+exp2 -> P in 16x16x16 A-layout
// -> 4x PV MFMA. Max-free softmax; normalize at end.
__global__ __launch_bounds__(256, 4) void attn(const u16* __restrict__ Q, const u16* __restrict__ Kb,
                                               const u16* __restrict__ Vt, const float* __restrict__ RBs,
                                               u16* __restrict__ O) {
    __shared__ __align__(16) u16 kbuf[2][32 * 32];   // [key][d], 16B chunk cols XOR-swizzled
    __shared__ __align__(16) u16 vbuf[2][32 * 32];   // [d][key], 16B chunk cols XOR-swizzled
    const int tid = threadIdx.x;
    const int wave = tid >> 6, lane = tid & 63;
    const int quad = lane >> 4, l15 = lane & 15;
    const int blk = blockIdx.x;
    const int bh = ((blk >> 7) << 3) + (blk & 7);
    const int qt = (blk >> 3) & 15;
    const int b = bh >> 3, h = bh & 7;
    const int qbase = qt * 64 + wave * 16;
    const size_t bhL = (size_t)bh * 1024;

    const bf16x8 qf = *(const bf16x8*)&Q[(bhL + qbase + l15) * 32 + quad * 8];   // Q[query=l15][d]
    const float* brow0 = RBs + (size_t)h * 3969
                         + (32 - (qbase >> 5)) * 32 + 32 - (qbase & 31) - l15 + quad * 4;
    // staging (wave 0): lane covers LDS row srow = lane>>2, LDS chunk col lane&3, whose content
    // must be global chunk col sgcol = (lane&3) ^ ((srow>>1)&3) = (lane&3) ^ ((lane>>3)&3).
    const int srow = lane >> 2;
    const int sgcol = (lane & 3) ^ ((lane >> 3) & 3);
    const u16* ksrc = &Kb[bhL * 32];                                    // + kb*32 per chunk
    const u16* vsrc_lo = &Vt[(((size_t)bh * 32) + srow) << 10];         // V^T rows d=0..15
    const u16* vsrc_hi = &Vt[(((size_t)bh * 32) + 16 + srow) << 10];    // V^T rows d=16..31

    float lsum = 0.f;
    f32x4 o_lo{0.f, 0.f, 0.f, 0.f}, o_hi{0.f, 0.f, 0.f, 0.f};

#define STAGE(buf, c) do {                                                       \
        const int kb_ = (c) * 32;                                                \
        async_cp16(ksrc + kb_ * 32 + srow * 32 + sgcol * 8, &kbuf[buf][0]);      \
        async_cp16(ksrc + kb_ * 32 + 512 + srow * 32 + sgcol * 8, &kbuf[buf][512]); \
        async_cp16(vsrc_lo + kb_ + sgcol * 8, &vbuf[buf][0]);                    \
        async_cp16(vsrc_hi + kb_ + sgcol * 8, &vbuf[buf][512]);                  \
    } while (0)

    if (wave == 0) STAGE(0, 0);
    __syncthreads();

    // reader-side swizzle terms (row-pair XOR): rows l15 and 16+l15 share (l15>>1)&3
    const int swz = (l15 >> 1) & 3;
    const int kcol = (quad ^ swz) * 8;                         // u16 offset of 16B chunk
    const int g0 = (2 * ((quad >> 1) ^ swz) + (quad & 1)) * 4;       // 8B granule, keys quad*4
    const int g1 = (2 * (((quad >> 1) + 2) ^ swz) + (quad & 1)) * 4; // 8B granule, keys 16+quad*4

    for (int c = 0; c < 32; c++) {                   // key chunk = one image row (yj == c)
        const int cur = c & 1;
        if (wave == 0 && c < 31) STAGE(cur ^ 1, c + 1);   // prefetch next while computing
        const bf16x8 kf0 = *(const bf16x8*)&kbuf[cur][l15 * 32 + kcol];
        const bf16x8 kf1 = *(const bf16x8*)&kbuf[cur][(16 + l15) * 32 + kcol];
        const bf16x4 v00 = __builtin_bit_cast(bf16x4, *(const u16x4*)&vbuf[cur][l15 * 32 + g0]);
        const bf16x4 v10 = __builtin_bit_cast(bf16x4, *(const u16x4*)&vbuf[cur][l15 * 32 + g1]);
        const bf16x4 v01 = __builtin_bit_cast(bf16x4, *(const u16x4*)&vbuf[cur][(16 + l15) * 32 + g0]);
        const bf16x4 v11 = __builtin_bit_cast(bf16x4, *(const u16x4*)&vbuf[cur][(16 + l15) * 32 + g1]);
        const f32x4u b0 = *(const f32x4u*)(brow0 + c * 32);
        const f32x4u b1 = *(const f32x4u*)(brow0 + c * 32 + 16);
        const f32x4 z{0.f, 0.f, 0.f, 0.f};
        // swapped operands: S^T = K * Q^T -> lane holds S[query=l15][key=quad*4+r]
        f32x4 s0 = __builtin_amdgcn_mfma_f32_16x16x32_bf16(kf0, qf, z, 0, 0, 0);
        f32x4 s1 = __builtin_amdgcn_mfma_f32_16x16x32_bf16(kf1, qf, z, 0, 0, 0);
        bf16x4 p0, p1;
#pragma unroll
        for (int r = 0; r < 4; r++) {
            const float e0 = exp2f(s0[r] + b0[r]);
            const float e1 = exp2f(s1[r] + b1[r]);
            lsum += e0 + e1;
            p0[r] = (bf16)e0;
            p1[r] = (bf16)e1;
        }
        o_lo = pv_mfma(p0, v00, o_lo);
        o_hi = pv_mfma(p0, v01, o_hi);
        o_lo = pv_mfma(p1, v10, o_lo);
        o_hi = pv_mfma(p1, v11, o_hi);
        __syncthreads();   // stage(nxt) drained (wave0) + all waves done reading cur
    }
#undef STAGE
    // lsum on lane = partial row-sum for query l15; finish across quads
    lsum += __shfl_xor(lsum, 16);
    lsum += __shfl_xor(lsum, 32);
#pragma unroll
    for (int r = 0; r < 4; r++) {
        const float inv = 1.f / __shfl(lsum, quad * 4 + r);
        const int i = qbase + quad * 4 + r;
        O[((size_t)(b * 1024 + i) * 256) + h * 32 + l15] = bfbits(o_lo[r] * inv);
        O[((size_t)(b * 1024 + i) * 256) + h * 32 + 16 + l15] = bfbits(o_hi[r] * inv);
    }
}

extern "C" void kernel_launch(void* const* d_in, const int* in_sizes, int n_in,
                              void* d_out, int out_size, void* d_ws, size_t ws_size,
                              hipStream_t stream) {
    const float* x   = (const float*)d_in[0];
    const float* Qw  = (const float*)d_in[1];
    const float* Kw  = (const float*)d_in[2];
    const float* Vw  = (const float*)d_in[3];
    const float* Fw  = (const float*)d_in[4];
    const float* ffb = (const float*)d_in[5];
    const float* RB  = (const float*)d_in[6];
    // d_in[7] = rel_idx (int32): deterministic, computed analytically in-kernel.

    u16* ws = (u16*)d_ws;
    u16* xf = ws;                   // 8192 x 256 bf16 (4 MB)   ... later reused as ob
    u16* wt = xf + 2097152;         // 1024 x 256 bf16 (0.5 MB) [Qw^T|Kw^T|Vw^T|ffw^T]
    u16* q  = wt + 262144;          // (b,h,l,d)  bf16 (4 MB), pre-scaled by log2e
    u16* kk = q  + 2097152;         // (b,h,l,d)  bf16 (4 MB)
    u16* vt = kk + 2097152;         // (b,h,d,l)  bf16 (4 MB)
    float* RBs = (float*)(vt + 2097152);   // 8 x 3969 fp32 (127 KB), bias * log2e
    u16* ob = xf;                   // (b,l,h*32+d) bf16 — aliases xf (dead after V proj)

    prep<<<dim3(608), 256, 0, stream>>>(x, Qw, Kw, Vw, Fw, RB, xf, wt, RBs);
    gemm_fused<<<dim3(1536), 256, 0, stream>>>(xf, wt, q, kk, vt, nullptr, nullptr, nullptr, 0); // QK + V^T
    attn<<<dim3(1024), 256, 0, stream>>>(q, kk, vt, RBs, ob);
    gemm_fused<<<dim3(512), 256, 0, stream>>>(xf, wt, q, kk, vt, ob, (float*)d_out, ffb, 2);     // FF
}